// Round 20
// baseline (135.060 us; speedup 1.0000x reference)
//
#include <hip/hip_runtime.h>
#include <hip/hip_bf16.h>
#include <hip/hip_fp16.h>

#define N_NODES 100000
#define N_EDGES 1600000
#define NBUCK ((N_NODES + 255) >> 8)   // 391 buckets of 256 nodes
#define CAP 8192                        // fixed region capacity per bucket (mean ~4096)
#define NMT (N_NODES / 16)              // 6250 M-tiles (MFMA mlp2)
#define SBLK 512                        // k_stage blocks
#define SCHUNK ((N_EDGES + SBLK - 1) / SBLK)  // 3125 edges per block

typedef _Float16 f16x8 __attribute__((ext_vector_type(8)));
typedef float f32x4 __attribute__((ext_vector_type(4)));

__device__ inline float2 h2_to_f2(unsigned int u) {
    __half2 h = *reinterpret_cast<__half2*>(&u);
    return __half22float2(h);
}

// ---------------------------------------------------------------------------
// Zero bcursor + gsum (tiny; NOT hipMemsetAsync — rocclr blit node overhead)
// ---------------------------------------------------------------------------
__global__ void k_zero(int* __restrict__ p, int n) {
    for (int i = threadIdx.x; i < n; i += 256) p[i] = 0;
}

// ---------------------------------------------------------------------------
// CSR build pass 1: stage edges into fixed-capacity bucket regions with
// LDS-grouped coalesced writes (round-19 proven).
// ---------------------------------------------------------------------------
__global__ __launch_bounds__(512) void k_stage(const int* __restrict__ src,
                                               const int* __restrict__ dst,
                                               int* __restrict__ bcursor,
                                               unsigned int* __restrict__ stage) {
    __shared__ int h[512];
    __shared__ int loc[512];
    __shared__ int base[NBUCK];
    __shared__ int cur[NBUCK];
    __shared__ unsigned int buf[SCHUNK];
    __shared__ int gidx[SCHUNK];
    const int tid = threadIdx.x;
    const int c0 = blockIdx.x * SCHUNK;
    const int c1 = (c0 + SCHUNK < N_EDGES) ? (c0 + SCHUNK) : N_EDGES;

    h[tid] = 0;
    if (tid < NBUCK) cur[tid] = 0;
    __syncthreads();

    for (int e = c0 + tid; e < c1; e += 512)
        atomicAdd(&h[dst[e] >> 8], 1);
    __syncthreads();

    int v = h[tid];
    loc[tid] = v;
    __syncthreads();
    for (int d = 1; d < 512; d <<= 1) {
        int t = (tid >= d) ? loc[tid - d] : 0;
        __syncthreads();
        loc[tid] += t;
        __syncthreads();
    }
    int inc = loc[tid];
    __syncthreads();
    loc[tid] = inc - v;
    if (tid < NBUCK && v > 0) base[tid] = atomicAdd(&bcursor[tid], v);
    __syncthreads();

    for (int e = c0 + tid; e < c1; e += 512) {
        int d = dst[e];
        int b = d >> 8;
        int pos = loc[b] + atomicAdd(&cur[b], 1);
        buf[pos] = ((unsigned int)(d & 255) << 17) | (unsigned int)src[e];
        int gpos = base[b] + (pos - loc[b]);
        gidx[pos] = (gpos < CAP) ? (b * CAP + gpos) : -1;
    }
    __syncthreads();

    const int cnt = c1 - c0;
    for (int i = tid; i < cnt; i += 512) {
        int g = gidx[i];
        if (g >= 0) stage[g] = buf[i];
    }
}

// ---------------------------------------------------------------------------
// CSR build pass 2 + FUSED LAYER 1. One block (512 thr) per bucket:
//  ph 1-4: LDS counting-sort in place; emit row_start/deg; write sorted csr.
//  ph 5: layer-1 for this bucket's 256 nodes — neighbor ids read from the
//        LDS-resident sorted list (no global csr re-read), x from L2
//        (3.2MB, L2-fits). 8 waves x 32 nodes; proven 8-slot gather +
//        shfl reduce + 8->64 MLP (weights loaded at phase start only).
// ---------------------------------------------------------------------------
__global__ __launch_bounds__(512) void k_bsort_l1(
    unsigned int* __restrict__ stage, const int* __restrict__ bcursor,
    int* __restrict__ row_start, int* __restrict__ deg,
    const float* __restrict__ x, const float* __restrict__ W1l,
    const float* __restrict__ b1, const float* __restrict__ W1r,
    __half* __restrict__ h1h) {
    __shared__ int off[257];
    __shared__ int cur[256];
    __shared__ unsigned int out[CAP];
    const int b = blockIdx.x;
    int cnt = bcursor[b];
    if (cnt > CAP) cnt = CAP;
    const int s = b * CAP;
    const int tid = threadIdx.x;

    if (tid < 256) cur[tid] = 0;
    __syncthreads();
    for (int i = tid; i < cnt; i += 512)
        atomicAdd(&cur[stage[s + i] >> 17], 1);
    __syncthreads();
    int v = 0;
    if (tid < 256) {
        v = cur[tid];
        off[tid] = v;
    }
    __syncthreads();
    for (int d = 1; d < 256; d <<= 1) {
        int t = 0;
        if (tid < 256 && tid >= d) t = off[tid - d];
        __syncthreads();
        if (tid < 256) off[tid] += t;
        __syncthreads();
    }
    if (tid < 256) {
        int ex = off[tid] - v;
        off[tid] = ex;
        cur[tid] = 0;
        int node = b * 256 + tid;
        if (node < N_NODES) {
            row_start[node] = s + ex;
            deg[node] = v;
        }
        if (tid == 255) off[256] = cnt;
    }
    __syncthreads();

    for (int i = tid; i < cnt; i += 512) {
        unsigned int p = stage[s + i];
        int l = p >> 17;
        int pos = off[l] + atomicAdd(&cur[l], 1);
        out[pos] = p & 0x1FFFFu;
    }
    __syncthreads();
    for (int i = tid; i < cnt; i += 512)
        stage[s + i] = out[i];

    // ---- phase 5: fused layer 1 (no extra barrier needed beyond this one:
    // out[] and off[] are read-only from here) ----
    __syncthreads();
    const int lane = tid & 63;
    const int w = tid >> 6;          // 8 waves
    const int g = lane >> 3;         // neighbor slot 0..7
    const int sub = lane & 7;        // feature 0..7

    float wl1[8], wr1[8];
#pragma unroll
    for (int k = 0; k < 8; k++) {
        wl1[k] = W1l[k * 64 + lane];
        wr1[k] = W1r[k * 64 + lane];
    }
    float bv = b1[lane];

    for (int local = w * 32; local < w * 32 + 32; ++local) {
        int node = b * 256 + local;
        if (node >= N_NODES) break;
        int rs = off[local];
        int re = off[local + 1];
        int dg = re - rs;
        float acc = 0.0f;
        int t = rs;
        for (; t + 16 <= re; t += 16) {
            int i0 = (int)out[t + g];
            int i1 = (int)out[t + 8 + g];
            acc += x[i0 * 8 + sub] + x[i1 * 8 + sub];
        }
        for (; t + 8 <= re; t += 8) {
            int i0 = (int)out[t + g];
            acc += x[i0 * 8 + sub];
        }
        int r = re - t;
        if (r > 0) {
            int ii = (int)out[(t + g < re) ? (t + g) : (re - 1)];
            float vv = x[ii * 8 + sub];
            if (g < r) acc += vv;
        }
        acc += __shfl_xor(acc, 8);
        acc += __shfl_xor(acc, 16);
        acc += __shfl_xor(acc, 32);
        float inv = 1.0f / fmaxf((float)dg, 1.0f);
        float mean = acc * inv;
        float xself = x[node * 8 + sub];
        float m[8], xk[8];
#pragma unroll
        for (int k = 0; k < 8; k++) {
            m[k]  = __shfl(mean, k);
            xk[k] = __shfl(xself, k);
        }
        float a = bv;
#pragma unroll
        for (int k = 0; k < 8; k++)
            a += m[k] * wl1[k] + xk[k] * wr1[k];
        h1h[(size_t)node * 64 + lane] = __float2half(fmaxf(a, 0.0f));
    }
}

// ---------------------------------------------------------------------------
// Layer 2 aggregation (round-12 proven version): one wave per node, fp16
// rows, 4 neighbors per load, 2x unrolled. Output mean2 as fp16.
// ---------------------------------------------------------------------------
__global__ __launch_bounds__(256) void agg2(
    const __half* __restrict__ h1h, const int* __restrict__ row_start,
    const int* __restrict__ deg, const int* __restrict__ csr,
    __half* __restrict__ mean2h) {
    const int lane = threadIdx.x & 63;
    const int g = lane >> 4;
    const int sub = lane & 15;

    const int gwid = (blockIdx.x * blockDim.x + threadIdx.x) >> 6;
    const int nwaves = (gridDim.x * blockDim.x) >> 6;

    for (int node = gwid; node < N_NODES; node += nwaves) {
        int rs = row_start[node];
        int dg = deg[node];
        int re = rs + dg;
        float4 acc = {0.f, 0.f, 0.f, 0.f};
        int t = rs;
        for (; t + 8 <= re; t += 8) {
            int i0 = csr[t + g];
            int i1 = csr[t + 4 + g];
            uint2 a = *(const uint2*)(h1h + i0 * 64 + sub * 4);
            uint2 b = *(const uint2*)(h1h + i1 * 64 + sub * 4);
            float2 a0 = h2_to_f2(a.x), a1 = h2_to_f2(a.y);
            float2 b0 = h2_to_f2(b.x), b1 = h2_to_f2(b.y);
            acc.x += a0.x + b0.x; acc.y += a0.y + b0.y;
            acc.z += a1.x + b1.x; acc.w += a1.y + b1.y;
        }
        for (; t + 4 <= re; t += 4) {
            int i0 = csr[t + g];
            uint2 a = *(const uint2*)(h1h + i0 * 64 + sub * 4);
            float2 a0 = h2_to_f2(a.x), a1 = h2_to_f2(a.y);
            acc.x += a0.x; acc.y += a0.y; acc.z += a1.x; acc.w += a1.y;
        }
        int r = re - t;
        if (r > 0) {
            int ii = csr[(t + g < re) ? (t + g) : (re - 1)];
            uint2 a = *(const uint2*)(h1h + ii * 64 + sub * 4);
            if (g < r) {
                float2 a0 = h2_to_f2(a.x), a1 = h2_to_f2(a.y);
                acc.x += a0.x; acc.y += a0.y; acc.z += a1.x; acc.w += a1.y;
            }
        }
#pragma unroll
        for (int m = 16; m <= 32; m <<= 1) {
            acc.x += __shfl_xor(acc.x, m);
            acc.y += __shfl_xor(acc.y, m);
            acc.z += __shfl_xor(acc.z, m);
            acc.w += __shfl_xor(acc.w, m);
        }
        float inv = 1.0f / fmaxf((float)dg, 1.0f);
        if (lane < 16) {
            __half2 o0 = __floats2half2_rn(acc.x * inv, acc.y * inv);
            __half2 o1 = __floats2half2_rn(acc.z * inv, acc.w * inv);
            uint2 pk;
            pk.x = *(unsigned int*)&o0;
            pk.y = *(unsigned int*)&o1;
            *(uint2*)(mean2h + node * 64 + sub * 4) = pk;
        }
    }
}

// ---------------------------------------------------------------------------
// Layer 2 MLP + global mean pool via MFMA 16x16x32 f16 (unconditional —
// __has_builtin guards cause host/device kernel-set mismatch).
// ---------------------------------------------------------------------------
__global__ __launch_bounds__(256) void mlp2_mfma(
    const __half* __restrict__ mean2h, const __half* __restrict__ h1h,
    const float* __restrict__ W2l, const float* __restrict__ b2,
    const float* __restrict__ W2r, float* __restrict__ gsum) {
    __shared__ float part[4][64];
    const int tid = threadIdx.x;
    const int lane = tid & 63;
    const int w = tid >> 6;
    const int row16 = lane & 15;
    const int grp = lane >> 4;

    f16x8 bf[4][4];
#pragma unroll
    for (int c = 0; c < 4; c++) {
        const float* Wsrc = (c < 2) ? W2l : W2r;
        int koff = (c & 1) * 32 + grp * 8;
#pragma unroll
        for (int nt = 0; nt < 4; nt++) {
            f16x8 t;
#pragma unroll
            for (int j = 0; j < 8; j++)
                t[j] = (_Float16)Wsrc[(koff + j) * 64 + nt * 16 + row16];
            bf[c][nt] = t;
        }
    }
    float bv[4];
#pragma unroll
    for (int nt = 0; nt < 4; nt++) bv[nt] = b2[nt * 16 + row16];
    asm volatile("" ::: "memory");

    const int gwid = (blockIdx.x * blockDim.x + tid) >> 6;
    const int nwaves = (gridDim.x * blockDim.x) >> 6;
    float pool[4] = {0.f, 0.f, 0.f, 0.f};

    for (int mt = gwid; mt < NMT; mt += nwaves) {
        int n0 = mt * 16;
        const __half* am = mean2h + (size_t)(n0 + row16) * 64 + grp * 8;
        const __half* ah = h1h    + (size_t)(n0 + row16) * 64 + grp * 8;
        f16x8 af[4];
        af[0] = *(const f16x8*)(am);
        af[1] = *(const f16x8*)(am + 32);
        af[2] = *(const f16x8*)(ah);
        af[3] = *(const f16x8*)(ah + 32);
#pragma unroll
        for (int nt = 0; nt < 4; nt++) {
            f32x4 acc = {bv[nt], bv[nt], bv[nt], bv[nt]};
#pragma unroll
            for (int c = 0; c < 4; c++)
                acc = __builtin_amdgcn_mfma_f32_16x16x32_f16(af[c], bf[c][nt],
                                                             acc, 0, 0, 0);
            pool[nt] += fmaxf(acc[0], 0.f) + fmaxf(acc[1], 0.f) +
                        fmaxf(acc[2], 0.f) + fmaxf(acc[3], 0.f);
        }
    }

#pragma unroll
    for (int nt = 0; nt < 4; nt++) {
        pool[nt] += __shfl_xor(pool[nt], 16);
        pool[nt] += __shfl_xor(pool[nt], 32);
    }
    if (lane < 16) {
#pragma unroll
        for (int nt = 0; nt < 4; nt++)
            part[w][nt * 16 + row16] = pool[nt];
    }
    __syncthreads();
    if (tid < 64)
        atomicAdd(&gsum[tid],
                  part[0][tid] + part[1][tid] + part[2][tid] + part[3][tid]);
}

// ---------------------------------------------------------------------------
// Head
// ---------------------------------------------------------------------------
__global__ void head(const float* __restrict__ gsum,
                     const float* __restrict__ fc1W, const float* __restrict__ fc1b,
                     const float* __restrict__ fc2W, const float* __restrict__ fc2b,
                     float* __restrict__ out) {
    __shared__ float g[64];
    __shared__ float a1[64];
    __shared__ float a2[10];
    int j = threadIdx.x;
    g[j] = gsum[j] * (1.0f / (float)N_NODES);
    __syncthreads();
    float acc = fc1b[j];
    for (int k = 0; k < 64; k++) acc += g[k] * fc1W[k * 64 + j];
    a1[j] = fmaxf(acc, 0.0f);
    __syncthreads();
    if (j < 10) {
        float acc2 = fc2b[j];
        for (int k = 0; k < 64; k++) acc2 += a1[k] * fc2W[k * 10 + j];
        a2[j] = acc2;
    }
    __syncthreads();
    if (j == 0) {
        float mx = -1e30f;
        for (int i = 0; i < 10; i++) mx = fmaxf(mx, a2[i]);
        float s = 0.0f;
        float e[10];
        for (int i = 0; i < 10; i++) {
            e[i] = expf(a2[i] - mx);
            s += e[i];
        }
        float invs = 1.0f / s;
        for (int i = 0; i < 10; i++) out[i] = e[i] * invs;
    }
}

extern "C" void kernel_launch(void* const* d_in, const int* in_sizes, int n_in,
                              void* d_out, int out_size, void* d_ws, size_t ws_size,
                              hipStream_t stream) {
    const float* x    = (const float*)d_in[0];
    const int*   ei   = (const int*)d_in[1];
    const float* W1l  = (const float*)d_in[2];
    const float* b1   = (const float*)d_in[3];
    const float* W1r  = (const float*)d_in[4];
    const float* W2l  = (const float*)d_in[5];
    const float* b2   = (const float*)d_in[6];
    const float* W2r  = (const float*)d_in[7];
    const float* fc1W = (const float*)d_in[8];
    const float* fc1b = (const float*)d_in[9];
    const float* fc2W = (const float*)d_in[10];
    const float* fc2b = (const float*)d_in[11];
    float* out = (float*)d_out;

    const int* src = ei;
    const int* dst = ei + N_EDGES;

    // workspace layout:
    //   h1h (N*64 half, 12.8MB) | stage/csr (NBUCK*CAP uint, 12.8MB) |
    //   mean2h (N*64 half, 12.8MB) | row_start (N) | deg (N) | bcursor (NB) | gsum
    __half* h1h    = (__half*)d_ws;
    unsigned int* stage = (unsigned int*)(h1h + (size_t)N_NODES * 64);
    int* csr       = (int*)stage;   // sorted in place by k_bsort_l1
    __half* mean2h = (__half*)(stage + (size_t)NBUCK * CAP);
    int* row_start = (int*)(mean2h + (size_t)N_NODES * 64);
    int* deg       = row_start + N_NODES;
    int* bcursor   = deg + N_NODES;
    float* gsum    = (float*)(bcursor + NBUCK);

    // zero bcursor + gsum (adjacent)
    k_zero<<<1, 256, 0, stream>>>(bcursor, NBUCK + 64);

    k_stage<<<SBLK, 512, 0, stream>>>(src, dst, bcursor, stage);
    k_bsort_l1<<<NBUCK, 512, 0, stream>>>(stage, bcursor, row_start, deg,
                                          x, W1l, b1, W1r, h1h);
    agg2<<<2048, 256, 0, stream>>>(h1h, row_start, deg, csr, mean2h);
    mlp2_mfma<<<512, 256, 0, stream>>>(mean2h, h1h, W2l, b2, W2r, gsum);
    head<<<1, 64, 0, stream>>>(gsum, fc1W, fc1b, fc2W, fc2b, out);
}

// Round 21
// 126.170 us; speedup vs baseline: 1.0705x; 1.0705x over previous
//
#include <hip/hip_runtime.h>
#include <hip/hip_bf16.h>
#include <hip/hip_fp16.h>

#define N_NODES 100000
#define N_EDGES 1600000
#define NBUCK ((N_NODES + 255) >> 8)   // 391 buckets of 256 nodes
#define CAP 8192                        // fixed region capacity per bucket (mean ~4096)
#define NMT (N_NODES / 16)              // 6250 M-tiles (MFMA mlp2)
#define SBLK 512                        // k_stage blocks
#define SCHUNK ((N_EDGES + SBLK - 1) / SBLK)  // 3125 edges per block

typedef _Float16 f16x8 __attribute__((ext_vector_type(8)));
typedef float f32x4 __attribute__((ext_vector_type(4)));

__device__ inline float2 h2_to_f2(unsigned int u) {
    __half2 h = *reinterpret_cast<__half2*>(&u);
    return __half22float2(h);
}

// ---------------------------------------------------------------------------
// Zero bcursor + gsum (tiny; NOT hipMemsetAsync — rocclr blit node overhead)
// ---------------------------------------------------------------------------
__global__ void k_zero(int* __restrict__ p, int n) {
    for (int i = threadIdx.x; i < n; i += 256) p[i] = 0;
}

// ---------------------------------------------------------------------------
// CSR build pass 1: stage edges into fixed-capacity bucket regions with
// LDS-grouped coalesced writes (round-19 proven).
// ---------------------------------------------------------------------------
__global__ __launch_bounds__(512) void k_stage(const int* __restrict__ src,
                                               const int* __restrict__ dst,
                                               int* __restrict__ bcursor,
                                               unsigned int* __restrict__ stage) {
    __shared__ int h[512];
    __shared__ int loc[512];
    __shared__ int base[NBUCK];
    __shared__ int cur[NBUCK];
    __shared__ unsigned int buf[SCHUNK];
    __shared__ int gidx[SCHUNK];
    const int tid = threadIdx.x;
    const int c0 = blockIdx.x * SCHUNK;
    const int c1 = (c0 + SCHUNK < N_EDGES) ? (c0 + SCHUNK) : N_EDGES;

    h[tid] = 0;
    if (tid < NBUCK) cur[tid] = 0;
    __syncthreads();

    for (int e = c0 + tid; e < c1; e += 512)
        atomicAdd(&h[dst[e] >> 8], 1);
    __syncthreads();

    int v = h[tid];
    loc[tid] = v;
    __syncthreads();
    for (int d = 1; d < 512; d <<= 1) {
        int t = (tid >= d) ? loc[tid - d] : 0;
        __syncthreads();
        loc[tid] += t;
        __syncthreads();
    }
    int inc = loc[tid];
    __syncthreads();
    loc[tid] = inc - v;
    if (tid < NBUCK && v > 0) base[tid] = atomicAdd(&bcursor[tid], v);
    __syncthreads();

    for (int e = c0 + tid; e < c1; e += 512) {
        int d = dst[e];
        int b = d >> 8;
        int pos = loc[b] + atomicAdd(&cur[b], 1);
        buf[pos] = ((unsigned int)(d & 255) << 17) | (unsigned int)src[e];
        int gpos = base[b] + (pos - loc[b]);
        gidx[pos] = (gpos < CAP) ? (b * CAP + gpos) : -1;
    }
    __syncthreads();

    const int cnt = c1 - c0;
    for (int i = tid; i < cnt; i += 512) {
        int g = gidx[i];
        if (g >= 0) stage[g] = buf[i];
    }
}

// ---------------------------------------------------------------------------
// CSR build pass 2: one block (512 thr) per bucket; LDS counting-sort IN
// PLACE. Emits row_start[node] = b*CAP + local_excl_offset and deg[node].
// (Kept SEPARATE from layer1 — R20 fusion starved the gather of TLP.)
// ---------------------------------------------------------------------------
__global__ __launch_bounds__(512) void k_bsort(unsigned int* __restrict__ stage,
                                               const int* __restrict__ bcursor,
                                               int* __restrict__ row_start,
                                               int* __restrict__ deg) {
    __shared__ int off[256];
    __shared__ int cur[256];
    __shared__ unsigned int out[CAP];
    const int b = blockIdx.x;
    int cnt = bcursor[b];
    if (cnt > CAP) cnt = CAP;
    const int s = b * CAP;
    const int tid = threadIdx.x;

    if (tid < 256) cur[tid] = 0;
    __syncthreads();
    for (int i = tid; i < cnt; i += 512)
        atomicAdd(&cur[stage[s + i] >> 17], 1);
    __syncthreads();
    int v = 0;
    if (tid < 256) {
        v = cur[tid];
        off[tid] = v;
    }
    __syncthreads();
    for (int d = 1; d < 256; d <<= 1) {
        int t = 0;
        if (tid < 256 && tid >= d) t = off[tid - d];
        __syncthreads();
        if (tid < 256) off[tid] += t;
        __syncthreads();
    }
    if (tid < 256) {
        int ex = off[tid] - v;
        off[tid] = ex;
        cur[tid] = 0;
        int node = b * 256 + tid;
        if (node < N_NODES) {
            row_start[node] = s + ex;
            deg[node] = v;
        }
    }
    __syncthreads();

    for (int i = tid; i < cnt; i += 512) {
        unsigned int p = stage[s + i];
        int l = p >> 17;
        int pos = off[l] + atomicAdd(&cur[l], 1);
        out[pos] = p & 0x1FFFFu;
    }
    __syncthreads();
    for (int i = tid; i < cnt; i += 512)
        stage[s + i] = out[i];
}

// ---------------------------------------------------------------------------
// Layer 1 fused: one wave per node, 8 neighbors per load, shfl-reduce,
// 8->64 MLP with weights in regs, write h1 as fp16.
// ---------------------------------------------------------------------------
__global__ __launch_bounds__(256) void layer1(
    const float* __restrict__ x, const int* __restrict__ row_start,
    const int* __restrict__ deg, const int* __restrict__ csr,
    const float* __restrict__ W1l, const float* __restrict__ b1,
    const float* __restrict__ W1r, __half* __restrict__ h1h) {
    const int lane = threadIdx.x & 63;
    const int g = lane >> 3;
    const int sub = lane & 7;

    float wl1[8], wr1[8];
#pragma unroll
    for (int k = 0; k < 8; k++) {
        wl1[k] = W1l[k * 64 + lane];
        wr1[k] = W1r[k * 64 + lane];
    }
    float bv = b1[lane];
    asm volatile("" ::: "memory");

    const int gwid = (blockIdx.x * blockDim.x + threadIdx.x) >> 6;
    const int nwaves = (gridDim.x * blockDim.x) >> 6;

    for (int node = gwid; node < N_NODES; node += nwaves) {
        int rs = row_start[node];
        int dg = deg[node];
        int re = rs + dg;
        float acc = 0.0f;
        int t = rs;
        for (; t + 16 <= re; t += 16) {
            int i0 = csr[t + g];
            int i1 = csr[t + 8 + g];
            acc += x[i0 * 8 + sub] + x[i1 * 8 + sub];
        }
        for (; t + 8 <= re; t += 8) {
            int i0 = csr[t + g];
            acc += x[i0 * 8 + sub];
        }
        int r = re - t;
        if (r > 0) {
            int ii = csr[(t + g < re) ? (t + g) : (re - 1)];
            float v = x[ii * 8 + sub];
            if (g < r) acc += v;
        }
        acc += __shfl_xor(acc, 8);
        acc += __shfl_xor(acc, 16);
        acc += __shfl_xor(acc, 32);
        float inv = 1.0f / fmaxf((float)dg, 1.0f);
        float mean = acc * inv;
        float xself = x[node * 8 + sub];
        float m[8], xk[8];
#pragma unroll
        for (int k = 0; k < 8; k++) {
            m[k]  = __shfl(mean, k);
            xk[k] = __shfl(xself, k);
        }
        float a = bv;
#pragma unroll
        for (int k = 0; k < 8; k++)
            a += m[k] * wl1[k] + xk[k] * wr1[k];
        h1h[node * 64 + lane] = __float2half(fmaxf(a, 0.0f));
    }
}

// ---------------------------------------------------------------------------
// Layer 2 aggregation (round-12 proven version): one wave per node, fp16
// rows, 4 neighbors per load, 2x unrolled. Output mean2 as fp16.
// ---------------------------------------------------------------------------
__global__ __launch_bounds__(256) void agg2(
    const __half* __restrict__ h1h, const int* __restrict__ row_start,
    const int* __restrict__ deg, const int* __restrict__ csr,
    __half* __restrict__ mean2h) {
    const int lane = threadIdx.x & 63;
    const int g = lane >> 4;
    const int sub = lane & 15;

    const int gwid = (blockIdx.x * blockDim.x + threadIdx.x) >> 6;
    const int nwaves = (gridDim.x * blockDim.x) >> 6;

    for (int node = gwid; node < N_NODES; node += nwaves) {
        int rs = row_start[node];
        int dg = deg[node];
        int re = rs + dg;
        float4 acc = {0.f, 0.f, 0.f, 0.f};
        int t = rs;
        for (; t + 8 <= re; t += 8) {
            int i0 = csr[t + g];
            int i1 = csr[t + 4 + g];
            uint2 a = *(const uint2*)(h1h + i0 * 64 + sub * 4);
            uint2 b = *(const uint2*)(h1h + i1 * 64 + sub * 4);
            float2 a0 = h2_to_f2(a.x), a1 = h2_to_f2(a.y);
            float2 b0 = h2_to_f2(b.x), b1 = h2_to_f2(b.y);
            acc.x += a0.x + b0.x; acc.y += a0.y + b0.y;
            acc.z += a1.x + b1.x; acc.w += a1.y + b1.y;
        }
        for (; t + 4 <= re; t += 4) {
            int i0 = csr[t + g];
            uint2 a = *(const uint2*)(h1h + i0 * 64 + sub * 4);
            float2 a0 = h2_to_f2(a.x), a1 = h2_to_f2(a.y);
            acc.x += a0.x; acc.y += a0.y; acc.z += a1.x; acc.w += a1.y;
        }
        int r = re - t;
        if (r > 0) {
            int ii = csr[(t + g < re) ? (t + g) : (re - 1)];
            uint2 a = *(const uint2*)(h1h + ii * 64 + sub * 4);
            if (g < r) {
                float2 a0 = h2_to_f2(a.x), a1 = h2_to_f2(a.y);
                acc.x += a0.x; acc.y += a0.y; acc.z += a1.x; acc.w += a1.y;
            }
        }
#pragma unroll
        for (int m = 16; m <= 32; m <<= 1) {
            acc.x += __shfl_xor(acc.x, m);
            acc.y += __shfl_xor(acc.y, m);
            acc.z += __shfl_xor(acc.z, m);
            acc.w += __shfl_xor(acc.w, m);
        }
        float inv = 1.0f / fmaxf((float)dg, 1.0f);
        if (lane < 16) {
            __half2 o0 = __floats2half2_rn(acc.x * inv, acc.y * inv);
            __half2 o1 = __floats2half2_rn(acc.z * inv, acc.w * inv);
            uint2 pk;
            pk.x = *(unsigned int*)&o0;
            pk.y = *(unsigned int*)&o1;
            *(uint2*)(mean2h + node * 64 + sub * 4) = pk;
        }
    }
}

// ---------------------------------------------------------------------------
// Layer 2 MLP + global mean pool via MFMA 16x16x32 f16 (unconditional —
// __has_builtin guards cause host/device kernel-set mismatch).
// ---------------------------------------------------------------------------
__global__ __launch_bounds__(256) void mlp2_mfma(
    const __half* __restrict__ mean2h, const __half* __restrict__ h1h,
    const float* __restrict__ W2l, const float* __restrict__ b2,
    const float* __restrict__ W2r, float* __restrict__ gsum) {
    __shared__ float part[4][64];
    const int tid = threadIdx.x;
    const int lane = tid & 63;
    const int w = tid >> 6;
    const int row16 = lane & 15;
    const int grp = lane >> 4;

    f16x8 bf[4][4];
#pragma unroll
    for (int c = 0; c < 4; c++) {
        const float* Wsrc = (c < 2) ? W2l : W2r;
        int koff = (c & 1) * 32 + grp * 8;
#pragma unroll
        for (int nt = 0; nt < 4; nt++) {
            f16x8 t;
#pragma unroll
            for (int j = 0; j < 8; j++)
                t[j] = (_Float16)Wsrc[(koff + j) * 64 + nt * 16 + row16];
            bf[c][nt] = t;
        }
    }
    float bv[4];
#pragma unroll
    for (int nt = 0; nt < 4; nt++) bv[nt] = b2[nt * 16 + row16];
    asm volatile("" ::: "memory");

    const int gwid = (blockIdx.x * blockDim.x + tid) >> 6;
    const int nwaves = (gridDim.x * blockDim.x) >> 6;
    float pool[4] = {0.f, 0.f, 0.f, 0.f};

    for (int mt = gwid; mt < NMT; mt += nwaves) {
        int n0 = mt * 16;
        const __half* am = mean2h + (size_t)(n0 + row16) * 64 + grp * 8;
        const __half* ah = h1h    + (size_t)(n0 + row16) * 64 + grp * 8;
        f16x8 af[4];
        af[0] = *(const f16x8*)(am);
        af[1] = *(const f16x8*)(am + 32);
        af[2] = *(const f16x8*)(ah);
        af[3] = *(const f16x8*)(ah + 32);
#pragma unroll
        for (int nt = 0; nt < 4; nt++) {
            f32x4 acc = {bv[nt], bv[nt], bv[nt], bv[nt]};
#pragma unroll
            for (int c = 0; c < 4; c++)
                acc = __builtin_amdgcn_mfma_f32_16x16x32_f16(af[c], bf[c][nt],
                                                             acc, 0, 0, 0);
            pool[nt] += fmaxf(acc[0], 0.f) + fmaxf(acc[1], 0.f) +
                        fmaxf(acc[2], 0.f) + fmaxf(acc[3], 0.f);
        }
    }

#pragma unroll
    for (int nt = 0; nt < 4; nt++) {
        pool[nt] += __shfl_xor(pool[nt], 16);
        pool[nt] += __shfl_xor(pool[nt], 32);
    }
    if (lane < 16) {
#pragma unroll
        for (int nt = 0; nt < 4; nt++)
            part[w][nt * 16 + row16] = pool[nt];
    }
    __syncthreads();
    if (tid < 64)
        atomicAdd(&gsum[tid],
                  part[0][tid] + part[1][tid] + part[2][tid] + part[3][tid]);
}

// ---------------------------------------------------------------------------
// Head
// ---------------------------------------------------------------------------
__global__ void head(const float* __restrict__ gsum,
                     const float* __restrict__ fc1W, const float* __restrict__ fc1b,
                     const float* __restrict__ fc2W, const float* __restrict__ fc2b,
                     float* __restrict__ out) {
    __shared__ float g[64];
    __shared__ float a1[64];
    __shared__ float a2[10];
    int j = threadIdx.x;
    g[j] = gsum[j] * (1.0f / (float)N_NODES);
    __syncthreads();
    float acc = fc1b[j];
    for (int k = 0; k < 64; k++) acc += g[k] * fc1W[k * 64 + j];
    a1[j] = fmaxf(acc, 0.0f);
    __syncthreads();
    if (j < 10) {
        float acc2 = fc2b[j];
        for (int k = 0; k < 64; k++) acc2 += a1[k] * fc2W[k * 10 + j];
        a2[j] = acc2;
    }
    __syncthreads();
    if (j == 0) {
        float mx = -1e30f;
        for (int i = 0; i < 10; i++) mx = fmaxf(mx, a2[i]);
        float s = 0.0f;
        float e[10];
        for (int i = 0; i < 10; i++) {
            e[i] = expf(a2[i] - mx);
            s += e[i];
        }
        float invs = 1.0f / s;
        for (int i = 0; i < 10; i++) out[i] = e[i] * invs;
    }
}

extern "C" void kernel_launch(void* const* d_in, const int* in_sizes, int n_in,
                              void* d_out, int out_size, void* d_ws, size_t ws_size,
                              hipStream_t stream) {
    const float* x    = (const float*)d_in[0];
    const int*   ei   = (const int*)d_in[1];
    const float* W1l  = (const float*)d_in[2];
    const float* b1   = (const float*)d_in[3];
    const float* W1r  = (const float*)d_in[4];
    const float* W2l  = (const float*)d_in[5];
    const float* b2   = (const float*)d_in[6];
    const float* W2r  = (const float*)d_in[7];
    const float* fc1W = (const float*)d_in[8];
    const float* fc1b = (const float*)d_in[9];
    const float* fc2W = (const float*)d_in[10];
    const float* fc2b = (const float*)d_in[11];
    float* out = (float*)d_out;

    const int* src = ei;
    const int* dst = ei + N_EDGES;

    // workspace layout:
    //   h1h (N*64 half, 12.8MB) | stage/csr (NBUCK*CAP uint, 12.8MB) |
    //   mean2h (N*64 half, 12.8MB) | row_start (N) | deg (N) | bcursor (NB) | gsum
    __half* h1h    = (__half*)d_ws;
    unsigned int* stage = (unsigned int*)(h1h + (size_t)N_NODES * 64);
    int* csr       = (int*)stage;   // sorted in place by k_bsort
    __half* mean2h = (__half*)(stage + (size_t)NBUCK * CAP);
    int* row_start = (int*)(mean2h + (size_t)N_NODES * 64);
    int* deg       = row_start + N_NODES;
    int* bcursor   = deg + N_NODES;
    float* gsum    = (float*)(bcursor + NBUCK);

    // zero bcursor + gsum (adjacent)
    k_zero<<<1, 256, 0, stream>>>(bcursor, NBUCK + 64);

    k_stage<<<SBLK, 512, 0, stream>>>(src, dst, bcursor, stage);
    k_bsort<<<NBUCK, 512, 0, stream>>>(stage, bcursor, row_start, deg);
    layer1<<<2048, 256, 0, stream>>>(x, row_start, deg, csr, W1l, b1, W1r, h1h);
    agg2<<<2048, 256, 0, stream>>>(h1h, row_start, deg, csr, mean2h);
    mlp2_mfma<<<512, 256, 0, stream>>>(mean2h, h1h, W2l, b2, W2r, gsum);
    head<<<1, 64, 0, stream>>>(gsum, fc1W, fc1b, fc2W, fc2b, out);
}